// Round 4
// baseline (29.079 us; speedup 1.0000x reference)
//
#include <hip/hip_runtime.h>
#include <math.h>

#define BATCH   512
#define IN_DIM  256
#define OUT_DIM 256
#define NDEG    6     // degree+1

// Block geometry (proven in R3): 256 threads = 8 o-lanes (minor) x 32
// i-segments; each thread keeps 16 b-accumulators so every coefficient
// load is reused 16x.
#define OT    8     // o per block
#define NSEG  32    // i-segments per block
#define ISEG  8     // i's per segment (NSEG*ISEG == IN_DIM)
#define NB    16    // b per block (register accumulators per thread)

// ---------------------------------------------------------------------------
// LSE_d(x*d + w_d) = log( sum_d e^{w_d} * t^d ),  t = e^x.
// out[b,o] = ln2 * sum_i [ log2 P_io(t) - log2 Q_io(t) ]
// R4: (P,Q) evaluated together via v_pk_fma_f32 (packed dual-f32 Horner,
// coefficients pre-interleaved (p_d,q_d)); log2 batched over pairs of i
// (P_i*P_{i+1} <= ~2e22, f32-safe) to halve quarter-rate trans ops.
// ---------------------------------------------------------------------------

typedef float v2f __attribute__((ext_vector_type(2)));

__device__ __forceinline__ v2f pk_fma(v2f a, v2f b, v2f c) {
    v2f d;
    asm("v_pk_fma_f32 %0, %1, %2, %3" : "=v"(d) : "v"(a), "v"(b), "v"(c));
    return d;
}
__device__ __forceinline__ v2f pk_mul(v2f a, v2f b) {
    v2f d;
    asm("v_pk_mul_f32 %0, %1, %2" : "=v"(d) : "v"(a), "v"(b));
    return d;
}

// Layout: pkT[(i*3+w)*256 + o] = float4 of interleaved pairs:
//   w=0: (p0,q0,p1,q1)  w=1: (p2,q2,p3,q3)  w=2: (p4,q4,p5,q5)
__global__ void prep_pack(const float* __restrict__ wp,
                          const float* __restrict__ wq,
                          float4* __restrict__ pkT) {
    int j = blockIdx.x * blockDim.x + threadIdx.x;   // j = i*OUT_DIM + o
    if (j >= IN_DIM * OUT_DIM) return;
    const int i = j >> 8, o = j & 255;
    const float2* wp2 = (const float2*)wp;
    const float2* wq2 = (const float2*)wq;
    float2 p0 = wp2[j * 3], p1 = wp2[j * 3 + 1], p2 = wp2[j * 3 + 2];
    float2 q0 = wq2[j * 3], q1 = wq2[j * 3 + 1], q2 = wq2[j * 3 + 2];
    pkT[(i * 3 + 0) * OUT_DIM + o] =
        make_float4(__expf(p0.x), __expf(q0.x), __expf(p0.y), __expf(q0.y));
    pkT[(i * 3 + 1) * OUT_DIM + o] =
        make_float4(__expf(p1.x), __expf(q1.x), __expf(p1.y), __expf(q1.y));
    pkT[(i * 3 + 2) * OUT_DIM + o] =
        make_float4(__expf(p2.x), __expf(q2.x), __expf(p2.y), __expf(q2.y));
}

// Grid = (OUT_DIM/OT = 32, BATCH/NB = 32) = 1024 blocks = 4/CU.
__launch_bounds__(256, 4)
__global__ void tropical_main(const float* __restrict__ x,
                              const float4* __restrict__ pkT,
                              float* __restrict__ out) {
    // Phase A: t[b][i], 16 b x 256 i (4096 f). Phase B: reduce buffer,
    // NSEG slabs of stride NB*OT+1=129 (4128 f). Shared allocation.
    __shared__ float lds[NSEG * (NB * OT + 1)];   // 4128 floats

    const int tid = threadIdx.x;
    const int o_l = tid & (OT - 1);
    const int seg = tid >> 3;
    const int o   = blockIdx.x * OT + o_l;
    const int b0  = blockIdx.y * NB;

    // ---- stage t = exp(x): 16 b-rows x 256 i (R3's proven pattern) ----
    {
        const int br  = tid >> 4;
        const int s16 = tid & 15;
        const float4* xr = (const float4*)(x + (size_t)(b0 + br) * IN_DIM) + s16 * 4;
#pragma unroll
        for (int k = 0; k < 4; ++k) {
            const float4 v = xr[k];
            const int base = br * IN_DIM + s16 * 16 + k * 4;
            lds[base + 0] = __expf(v.x);
            lds[base + 1] = __expf(v.y);
            lds[base + 2] = __expf(v.z);
            lds[base + 3] = __expf(v.w);
        }
    }
    __syncthreads();

    float acc[NB];
#pragma unroll
    for (int b = 0; b < NB; ++b) acc[b] = 0.f;

    const int i0 = seg * ISEG;
    const float4* __restrict__ cbase = pkT + (size_t)(i0 * 3) * OUT_DIM + o;
    const float* __restrict__ tbase = lds + i0;

    for (int g = 0; g < ISEG / 2; ++g) {          // i handled in pairs
        const int iA = 2 * g, iB = 2 * g + 1;
        const float4 a0 = cbase[(iA * 3 + 0) * OUT_DIM];
        const float4 a1 = cbase[(iA * 3 + 1) * OUT_DIM];
        const float4 a2 = cbase[(iA * 3 + 2) * OUT_DIM];
        const float4 e0 = cbase[(iB * 3 + 0) * OUT_DIM];
        const float4 e1 = cbase[(iB * 3 + 1) * OUT_DIM];
        const float4 e2 = cbase[(iB * 3 + 2) * OUT_DIM];
        const v2f CA0 = {a0.x, a0.y}, CA1 = {a0.z, a0.w};
        const v2f CA2 = {a1.x, a1.y}, CA3 = {a1.z, a1.w};
        const v2f CA4 = {a2.x, a2.y}, CA5 = {a2.z, a2.w};
        const v2f CB0 = {e0.x, e0.y}, CB1 = {e0.z, e0.w};
        const v2f CB2 = {e1.x, e1.y}, CB3 = {e1.z, e1.w};
        const v2f CB4 = {e2.x, e2.y}, CB5 = {e2.z, e2.w};

#pragma unroll
        for (int b = 0; b < NB; ++b) {
            const float t0 = tbase[b * IN_DIM + iA];   // LDS broadcast
            const float t1 = tbase[b * IN_DIM + iB];
            const v2f T0 = {t0, t0};
            const v2f T1 = {t1, t1};
            v2f PQ0 = pk_fma(CA5, T0, CA4);            // packed Horner (P,Q)
            PQ0 = pk_fma(PQ0, T0, CA3);
            PQ0 = pk_fma(PQ0, T0, CA2);
            PQ0 = pk_fma(PQ0, T0, CA1);
            PQ0 = pk_fma(PQ0, T0, CA0);
            v2f PQ1 = pk_fma(CB5, T1, CB4);
            PQ1 = pk_fma(PQ1, T1, CB3);
            PQ1 = pk_fma(PQ1, T1, CB2);
            PQ1 = pk_fma(PQ1, T1, CB1);
            PQ1 = pk_fma(PQ1, T1, CB0);
            const v2f pr = pk_mul(PQ0, PQ1);           // (P_A*P_B, Q_A*Q_B)
            acc[b] += __log2f(pr.x) - __log2f(pr.y);   // 1 log2 per triple
        }
    }

    __syncthreads();   // done with t; reuse LDS as reduce buffer
#pragma unroll
    for (int b = 0; b < NB; ++b)
        lds[seg * (NB * OT + 1) + b * OT + o_l] = acc[b];
    __syncthreads();

    if (tid < NB * OT) {
        const int br = tid >> 3, orr = tid & (OT - 1);
        float s = 0.f;
#pragma unroll
        for (int g2 = 0; g2 < NSEG; ++g2)
            s += lds[g2 * (NB * OT + 1) + br * OT + orr];
        out[(size_t)(b0 + br) * OUT_DIM + blockIdx.x * OT + orr] =
            s * 0.6931471805599453f;   // * ln2
    }
}

// Fallback (workspace too small): direct stabilized LSE.
__global__ void tropical_fallback(const float* __restrict__ x,
                                  const float* __restrict__ wp,
                                  const float* __restrict__ wq,
                                  float* __restrict__ out) {
    const int o = blockIdx.x * 16 + (threadIdx.x & 15);
    const int b = blockIdx.y * 16 + (threadIdx.x >> 4);
    float acc = 0.f;
    for (int i = 0; i < IN_DIM; ++i) {
        const float xv = x[b * IN_DIM + i];
        const float* p = wp + (size_t)(i * OUT_DIM + o) * NDEG;
        const float* q = wq + (size_t)(i * OUT_DIM + o) * NDEG;
        float lp[NDEG], lq[NDEG], mP = -1e30f, mQ = -1e30f;
#pragma unroll
        for (int d = 0; d < NDEG; ++d) {
            lp[d] = xv * d + p[d]; mP = fmaxf(mP, lp[d]);
            lq[d] = xv * d + q[d]; mQ = fmaxf(mQ, lq[d]);
        }
        float sP = 0.f, sQ = 0.f;
#pragma unroll
        for (int d = 0; d < NDEG; ++d) {
            sP += __expf(lp[d] - mP);
            sQ += __expf(lq[d] - mQ);
        }
        acc += (mP + __logf(sP)) - (mQ + __logf(sQ));
    }
    out[b * OUT_DIM + o] = acc;
}

extern "C" void kernel_launch(void* const* d_in, const int* in_sizes, int n_in,
                              void* d_out, int out_size, void* d_ws, size_t ws_size,
                              hipStream_t stream) {
    const float* x  = (const float*)d_in[0];
    // d_in[1] = slopes (arange(6)) — implicit in the polynomial powers.
    const float* wp = (const float*)d_in[2];
    const float* wq = (const float*)d_in[3];
    float* out = (float*)d_out;

    const size_t pk_bytes = (size_t)IN_DIM * OUT_DIM * 12 * sizeof(float);  // 3 MiB

    if (ws_size >= pk_bytes) {
        float4* pkT = (float4*)d_ws;
        prep_pack<<<(IN_DIM * OUT_DIM + 255) / 256, 256, 0, stream>>>(wp, wq, pkT);

        dim3 grid(OUT_DIM / OT, BATCH / NB);   // 32 x 32 = 1024 blocks
        tropical_main<<<grid, 256, 0, stream>>>(x, (const float4*)pkT, out);
    } else {
        dim3 grid(OUT_DIM / 16, BATCH / 16);
        tropical_fallback<<<grid, 256, 0, stream>>>(x, wp, wq, out);
    }
}